// Round 7
// baseline (392.025 us; speedup 1.0000x reference)
//
#include <hip/hip_runtime.h>
#include <hip/hip_bf16.h>
#include <math.h>

#define NN 100000      // nodes
#define NE 1600000     // edges
#define IN_DIM 6
#define EDGE_DIM 2
#define HH 5           // heads
#define CC 5           // channels/head
#define DD 25          // hidden = HH*CC
#define DS 32          // padded fp32 row stride (128B rows)
#define INV_SQRT_C 0.4472135954999579f
#define NBUK 200       // coarse dst buckets
#define BUKW 500       // nodes per bucket (200*500 = 100000 exact)
#define CAP 10000      // slab capacity per bucket (avg 8000, safe)
#define KPB 800        // k_part blocks
#define CH (NE / KPB)  // 2000 edges per k_part block
#define NPB 48         // nodes per block in edge kernel (12 per wave x 4 waves)
#define NBLK ((NN + NPB - 1) / NPB)   // 2084

// kv record: 128 B per node. Head h: 16-B chunk at byte 16h = [k0..k4, v0,v1,v2] bf16,
// plus 4-B at byte 80+4h = [v3,v4]. All lane loads naturally aligned.
// q record: 128 B per node, head h: 16-B chunk at byte 16h = [q0..q4, pad].

__device__ __forceinline__ unsigned int f2bf(float f) {   // fp32 -> bf16 bits (RNE)
    unsigned int u = __float_as_uint(f);
    return (u + 0x7fffu + ((u >> 16) & 1u)) >> 16;
}
__device__ __forceinline__ float bflo(unsigned int u) { return __uint_as_float(u << 16); }
__device__ __forceinline__ float bfhi(unsigned int u) { return __uint_as_float(u & 0xffff0000u); }

// ---------------- init: bucket cursors = slab bases ----------------
__global__ void k_init(int* __restrict__ cursor) {
    int i = threadIdx.x;
    if (i < NBUK) cursor[i] = i * CAP;
}

// ---------------- phase 1: bucket-partition edges ----------------
__global__ __launch_bounds__(256) void k_part(const int* __restrict__ ei,
                                              const float* __restrict__ ea,
                                              int* __restrict__ cursor,
                                              uint2* __restrict__ slab) {
    __shared__ int sdst[CH];        // 8 KB
    __shared__ int scnt[NBUK];
    __shared__ int sbase[NBUK];
    __shared__ int swp[NBUK];
    int base = blockIdx.x * CH;
    for (int i = threadIdx.x; i < NBUK; i += 256) scnt[i] = 0;
    __syncthreads();
    for (int i = threadIdx.x; i < CH; i += 256) {
        int dst = ei[NE + base + i];
        sdst[i] = dst;
        atomicAdd(&scnt[dst / BUKW], 1);
    }
    __syncthreads();
    for (int i = threadIdx.x; i < NBUK; i += 256) {
        sbase[i] = atomicAdd(&cursor[i], scnt[i]);
        swp[i] = 0;
    }
    __syncthreads();
    for (int i = threadIdx.x; i < CH; i += 256) {
        int dst = sdst[i];
        int b = dst / BUKW;
        int src = ei[base + i];
        float2 eav = ((const float2*)ea)[base + i];
        int p = sbase[b] + atomicAdd(&swp[b], 1);
        uint2 r;
        r.x = (unsigned)src | ((unsigned)(dst - b * BUKW) << 17);  // src:17b, dstLocal:9b
        r.y = f2bf(eav.x) | (f2bf(eav.y) << 16);
        slab[p] = r;
    }
}

// ---------------- bucket-base scan (1 block) ----------------
__global__ void k_scanB(const int* __restrict__ cursor, int* __restrict__ bucketOff,
                        int* __restrict__ rowptr) {
    __shared__ int s[256];
    int t = threadIdx.x;
    int v = (t < NBUK) ? (cursor[t] - t * CAP) : 0;
    s[t] = v;
    __syncthreads();
    for (int off = 1; off < 256; off <<= 1) {
        int u = (t >= off) ? s[t - off] : 0;
        __syncthreads();
        s[t] += u;
        __syncthreads();
    }
    if (t < NBUK) bucketOff[t] = s[t] - v;   // exclusive
    if (t == 0) rowptr[NN] = NE;
}

// ---------------- phase 2: per-bucket hist + scan + rowptr + place ----------------
__global__ __launch_bounds__(512) void k_place(const int* __restrict__ cursor,
                                               const uint2* __restrict__ slab,
                                               const int* __restrict__ bucketOff,
                                               int* __restrict__ rowptr,
                                               uint2* __restrict__ csr) {
    __shared__ int hist[BUKW];
    __shared__ int cur[BUKW];
    __shared__ int s[512];
    int b = blockIdx.x;
    int node0 = b * BUKW;
    int begin = b * CAP;
    int cnt = cursor[b] - begin;
    int bOff = bucketOff[b];
    for (int i = threadIdx.x; i < BUKW; i += 512) hist[i] = 0;
    __syncthreads();
    for (int i = threadIdx.x; i < cnt; i += 512) {
        uint2 r = slab[begin + i];
        atomicAdd(&hist[r.x >> 17], 1);
    }
    __syncthreads();
    int t = threadIdx.x;
    int v = (t < BUKW) ? hist[t] : 0;
    s[t] = v;
    __syncthreads();
    for (int off = 1; off < 512; off <<= 1) {
        int u = (t >= off) ? s[t - off] : 0;
        __syncthreads();
        s[t] += u;
        __syncthreads();
    }
    if (t < BUKW) {
        int o = bOff + s[t] - v;
        rowptr[node0 + t] = o;
        cur[t] = o;
    }
    __syncthreads();
    for (int i = threadIdx.x; i < cnt; i += 512) {
        uint2 r = slab[begin + i];         // L2 hit (just streamed)
        int dl = (int)(r.x >> 17);
        int p = atomicAdd(&cur[dl], 1);
        uint2 o;
        o.x = r.x & 0x1FFFFu;
        o.y = r.y;
        csr[p] = o;
    }
}

// ---------------- input projection ----------------
__global__ void k_input_proj(const float* __restrict__ x, const float* __restrict__ Wi,
                             const float* __restrict__ bi, float* __restrict__ h) {
    __shared__ float sW[IN_DIM * DD];
    __shared__ float sb[DD];
    int t = threadIdx.x;
    if (t < IN_DIM * DD) sW[t] = Wi[t];
    if (t < DD) sb[t] = bi[t];
    __syncthreads();
    int tid = blockIdx.x * blockDim.x + t;
    int n = tid / DD, d = tid - n * DD;
    if (n >= NN) return;
    float acc = sb[d];
    const float* xr = x + n * IN_DIM;
#pragma unroll
    for (int i = 0; i < IN_DIM; i++) acc += xr[i] * sW[i * DD + d];
    h[n * DS + d] = acc;
}

// ------- per-layer node pass: q/kv in head-chunked bf16 layout, skip in fp32 -------
__global__ void k_qkv_skip(const float* __restrict__ h,
                           const float* __restrict__ Wq, const float* __restrict__ bq,
                           const float* __restrict__ Wk, const float* __restrict__ bk,
                           const float* __restrict__ Wv, const float* __restrict__ bv,
                           const float* __restrict__ Ws, const float* __restrict__ bs,
                           __hip_bfloat16* __restrict__ q, __hip_bfloat16* __restrict__ kv,
                           float* __restrict__ hout) {
    __shared__ float sWq[DD * DD], sWk[DD * DD], sWv[DD * DD], sWs[DD * DD];
    __shared__ float sb[4 * DD];
    for (int i = threadIdx.x; i < DD * DD; i += blockDim.x) {
        sWq[i] = Wq[i]; sWk[i] = Wk[i]; sWv[i] = Wv[i]; sWs[i] = Ws[i];
    }
    if (threadIdx.x < DD) {
        sb[threadIdx.x]          = bq[threadIdx.x];
        sb[DD + threadIdx.x]     = bk[threadIdx.x];
        sb[2 * DD + threadIdx.x] = bv[threadIdx.x];
        sb[3 * DD + threadIdx.x] = bs[threadIdx.x];
    }
    __syncthreads();
    int tid = blockIdx.x * blockDim.x + threadIdx.x;
    int n = tid / DD, d = tid - n * DD;
    if (n >= NN) return;
    float aq = sb[d], ak = sb[DD + d], av = sb[2 * DD + d], asv = sb[3 * DD + d];
    const float* hr = h + (size_t)n * DS;
#pragma unroll
    for (int i = 0; i < DD; i++) {
        float hv = hr[i];
        aq  += hv * sWq[i * DD + d];
        ak  += hv * sWk[i * DD + d];
        av  += hv * sWv[i * DD + d];
        asv += hv * sWs[i * DD + d];
    }
    int h5 = d / 5, c5 = d - h5 * 5;
    size_t rb = (size_t)n * 64;      // row base in shorts (128 B rows)
    q[rb + 8 * h5 + c5] = __float2bfloat16(aq * INV_SQRT_C);   // fold 1/sqrt(C)
    kv[rb + 8 * h5 + c5] = __float2bfloat16(ak);               // k0..k4
    if (c5 < 3) kv[rb + 8 * h5 + 5 + c5] = __float2bfloat16(av);          // v0..v2
    else        kv[rb + 40 + 2 * h5 + (c5 - 3)] = __float2bfloat16(av);   // v3,v4
    hout[(size_t)n * DS + d] = asv;
}

// ---------------- fused edge pass: 5 lanes = 5 heads per node ----------------
// 12 nodes per wave (lanes 60-63 idle), 48 nodes per 256-thread block.
// Per edge: one coalesced dwordx4 (2 lines/group) + one dword (1 line/group) + shared rec.
__global__ __launch_bounds__(256) void k_edge_fused(
    const int* __restrict__ rowptr, const uint2* __restrict__ csr,
    const float* __restrict__ We, const __hip_bfloat16* __restrict__ q,
    const __hip_bfloat16* __restrict__ kv, float* __restrict__ hout) {
    __shared__ float sWe[EDGE_DIM * DD];
    if (threadIdx.x < EDGE_DIM * DD) sWe[threadIdx.x] = We[threadIdx.x];
    __syncthreads();
    int lane = threadIdx.x & 63;
    int wv   = threadIdx.x >> 6;
    int grp  = lane / 5;             // 0..12 (12 = idle lanes 60-63)
    int h    = lane - grp * 5;       // head
    int node = blockIdx.x * NPB + wv * 12 + grp;
    bool act = (grp < 12) && (node < NN);

    int beg = 0, end = 0;
    float qa0 = 0, qa1 = 0, qa2 = 0, qa3 = 0, qa4 = 0, qwx = 0, qwy = 0;
    if (act) {
        beg = rowptr[node];
        end = rowptr[node + 1];
        uint4 qc = *(const uint4*)(q + (size_t)node * 64 + 8 * h);  // 16-B aligned
        qa0 = bflo(qc.x); qa1 = bfhi(qc.x); qa2 = bflo(qc.y); qa3 = bfhi(qc.y); qa4 = bflo(qc.z);
        const float* wx = &sWe[5 * h];
        const float* wy = &sWe[DD + 5 * h];
        qwx = qa0 * wx[0] + qa1 * wx[1] + qa2 * wx[2] + qa3 * wx[3] + qa4 * wx[4];
        qwy = qa0 * wy[0] + qa1 * wy[1] + qa2 * wy[2] + qa3 * wy[3] + qa4 * wy[4];
    }

    float l = 0.f, Sx = 0.f, Sy = 0.f;
    float a0 = 0.f, a1 = 0.f, a2 = 0.f, a3 = 0.f, a4 = 0.f;

    for (int p = beg; p < end; ++p) {
        uint2 rec = csr[p];                        // same addr across the 5 lanes
        float eax = bflo(rec.y), eay = bfhi(rec.y);
        const __hip_bfloat16* base = kv + ((size_t)rec.x << 6);   // src * 64 shorts
        uint4 A = *(const uint4*)(base + 8 * h);                  // byte 16h, 16-B aligned
        unsigned int B = *(const unsigned int*)(base + 40 + 2 * h); // byte 80+4h, 4-B aligned
        float k0 = bflo(A.x), k1 = bfhi(A.x), k2 = bflo(A.y), k3 = bfhi(A.y), k4 = bflo(A.z);
        float v0 = bfhi(A.z), v1 = bflo(A.w), v2 = bfhi(A.w), v3 = bflo(B), v4 = bfhi(B);
        float s = qa0 * k0 + qa1 * k1 + qa2 * k2 + qa3 * k3 + qa4 * k4
                + eax * qwx + eay * qwy;
        float cf = __expf(s);
        l  += cf;
        Sx += cf * eax;
        Sy += cf * eay;
        a0 += cf * v0; a1 += cf * v1; a2 += cf * v2; a3 += cf * v3; a4 += cf * v4;
    }

    if (act) {
        float inv = 1.0f / (l + 1e-16f);
        const float* wx = &sWe[5 * h];
        const float* wy = &sWe[DD + 5 * h];
        float* ho = hout + (size_t)node * DS + 5 * h;
        ho[0] += (a0 + Sx * wx[0] + Sy * wy[0]) * inv;
        ho[1] += (a1 + Sx * wx[1] + Sy * wy[1]) * inv;
        ho[2] += (a2 + Sx * wx[2] + Sy * wy[2]) * inv;
        ho[3] += (a3 + Sx * wx[3] + Sy * wy[3]) * inv;
        ho[4] += (a4 + Sx * wx[4] + Sy * wy[4]) * inv;
    }
}

// ---------------- output head ----------------
__global__ void k_head(const float* __restrict__ h, const float* __restrict__ Wo,
                       const float* __restrict__ bo, float* __restrict__ out) {
    __shared__ float sW[DD];
    __shared__ float sb0;
    if (threadIdx.x < DD) sW[threadIdx.x] = Wo[threadIdx.x];
    if (threadIdx.x == 0) sb0 = bo[0];
    __syncthreads();
    int n = blockIdx.x * blockDim.x + threadIdx.x;
    if (n >= NN) return;
    float acc = sb0;
    const float* hr = h + (size_t)n * DS;
#pragma unroll
    for (int i = 0; i < DD; i++) acc += hr[i] * sW[i];
    out[n] = 1.0f / (1.0f + __expf(-acc));
}

extern "C" void kernel_launch(void* const* d_in, const int* in_sizes, int n_in,
                              void* d_out, int out_size, void* d_ws, size_t ws_size,
                              hipStream_t stream) {
    const float* x     = (const float*)d_in[0];
    const int*   ei    = (const int*)d_in[1];     // [2,E]: src=[0..E), dst=[E..2E)
    const float* ea    = (const float*)d_in[2];   // [E,2]
    const float* Wi    = (const float*)d_in[3];
    const float* bi    = (const float*)d_in[4];
    const float* Wq    = (const float*)d_in[5];
    const float* bq    = (const float*)d_in[6];
    const float* Wk    = (const float*)d_in[7];
    const float* bk    = (const float*)d_in[8];
    const float* Wv    = (const float*)d_in[9];
    const float* bv    = (const float*)d_in[10];
    const float* We    = (const float*)d_in[11];
    const float* Wskip = (const float*)d_in[12];
    const float* bskip = (const float*)d_in[13];
    const float* Wo    = (const float*)d_in[14];
    const float* bo    = (const float*)d_in[15];
    float* out = (float*)d_out;
    (void)in_sizes; (void)n_in; (void)out_size; (void)ws_size;

    char* wsb = (char*)d_ws;
    size_t off = 0;
    auto alloc = [&](size_t bytes) {
        void* p = wsb + off;
        off += (bytes + 127) & ~(size_t)127;
        return p;
    };
    uint2* slab   = (uint2*)alloc((size_t)NBUK * CAP * sizeof(uint2));       // 16 MB
    uint2* csr    = (uint2*)alloc((size_t)NE * sizeof(uint2));               // 12.8 MB
    __hip_bfloat16* kvrec = (__hip_bfloat16*)alloc((size_t)NN * 64 * 2);     // 12.8 MB
    __hip_bfloat16* qrec  = (__hip_bfloat16*)alloc((size_t)NN * 64 * 2);     // 12.8 MB
    float* hA     = (float*)alloc((size_t)NN * DS * sizeof(float));
    float* hB     = (float*)alloc((size_t)NN * DS * sizeof(float));
    int*   rowptr = (int*)alloc((size_t)(NN + 1) * sizeof(int));
    int*   cursor = (int*)alloc((size_t)NBUK * sizeof(int));
    int*   bucketOff = (int*)alloc((size_t)NBUK * sizeof(int));

    dim3 blk(256);
    int gN  = (NN + 255) / 256;         // 391
    int gND = (NN * DD + 255) / 256;    // 9766

    // CSR build (every call — ws is re-poisoned)
    k_init<<<1, blk, 0, stream>>>(cursor);
    k_part<<<KPB, blk, 0, stream>>>(ei, ea, cursor, slab);
    k_scanB<<<1, blk, 0, stream>>>(cursor, bucketOff, rowptr);
    k_place<<<NBUK, dim3(512), 0, stream>>>(cursor, slab, bucketOff, rowptr, csr);

    k_input_proj<<<gND, blk, 0, stream>>>(x, Wi, bi, hA);

    float* hc = hA;
    float* hn = hB;
    for (int l = 0; l < 3; l++) {
        k_qkv_skip<<<gND, blk, 0, stream>>>(hc,
                                            Wq + (size_t)l * DD * DD, bq + (size_t)l * DD,
                                            Wk + (size_t)l * DD * DD, bk + (size_t)l * DD,
                                            Wv + (size_t)l * DD * DD, bv + (size_t)l * DD,
                                            Wskip + (size_t)l * DD * DD, bskip + (size_t)l * DD,
                                            qrec, kvrec, hn);
        k_edge_fused<<<NBLK, blk, 0, stream>>>(rowptr, csr,
                                               We + (size_t)l * EDGE_DIM * DD,
                                               qrec, kvrec, hn);
        float* t = hc; hc = hn; hn = t;
    }
    k_head<<<gN, blk, 0, stream>>>(hc, Wo, bo, out);
}

// Round 8
// 381.468 us; speedup vs baseline: 1.0277x; 1.0277x over previous
//
#include <hip/hip_runtime.h>
#include <hip/hip_bf16.h>
#include <math.h>

#define NN 100000      // nodes
#define NE 1600000     // edges
#define IN_DIM 6
#define EDGE_DIM 2
#define HH 5           // heads
#define CC 5           // channels/head
#define DD 25          // hidden = HH*CC
#define DS 32          // padded fp32 row stride (128B rows)
#define INV_SQRT_C 0.4472135954999579f
#define NBUK 200       // coarse dst buckets
#define BUKW 500       // nodes per bucket (200*500 = 100000 exact)
#define CAP 10000      // slab capacity per bucket (avg 8000, >20 sigma safe)
#define KPB 800        // k_part blocks
#define CH (NE / KPB)  // 2000 edges per k_part block
#define NPB 48         // nodes per block in edge kernel (12 per wave x 4 waves)
#define NBLK ((NN + NPB - 1) / NPB)   // 2084

// q record: 80 B/node (40 shorts). Head h: 16-B chunk at short 40n + 8h = [q0..q4,pad3].
// kv record: 100 B/node (50 shorts). Head h: 20-B chunk at short 50n + 10h =
//            [k0..k4, v0..v4] -> 5 aligned dwords at byte 100n + 20h.

__device__ __forceinline__ unsigned int f2bf(float f) {   // fp32 -> bf16 bits (RNE)
    unsigned int u = __float_as_uint(f);
    return (u + 0x7fffu + ((u >> 16) & 1u)) >> 16;
}
__device__ __forceinline__ float bflo(unsigned int u) { return __uint_as_float(u << 16); }
__device__ __forceinline__ float bfhi(unsigned int u) { return __uint_as_float(u & 0xffff0000u); }

// ---------------- phase 1: bucket-partition edges (cursor holds per-bucket counts) ----------------
__global__ __launch_bounds__(256) void k_part(const int* __restrict__ ei,
                                              const float* __restrict__ ea,
                                              int* __restrict__ cursor,
                                              uint2* __restrict__ slab) {
    __shared__ int sdst[CH];        // 8 KB
    __shared__ int scnt[NBUK];
    __shared__ int sbase[NBUK];
    __shared__ int swp[NBUK];
    int base = blockIdx.x * CH;
    for (int i = threadIdx.x; i < NBUK; i += 256) scnt[i] = 0;
    __syncthreads();
    for (int i = threadIdx.x; i < CH; i += 256) {
        int dst = ei[NE + base + i];
        sdst[i] = dst;
        atomicAdd(&scnt[dst / BUKW], 1);
    }
    __syncthreads();
    for (int i = threadIdx.x; i < NBUK; i += 256) {
        sbase[i] = i * CAP + atomicAdd(&cursor[i], scnt[i]);
        swp[i] = 0;
    }
    __syncthreads();
    for (int i = threadIdx.x; i < CH; i += 256) {
        int dst = sdst[i];
        int b = dst / BUKW;
        int src = ei[base + i];
        float2 eav = ((const float2*)ea)[base + i];
        int p = sbase[b] + atomicAdd(&swp[b], 1);
        uint2 r;
        r.x = (unsigned)src | ((unsigned)(dst - b * BUKW) << 17);  // src:17b, dstLocal:9b
        r.y = f2bf(eav.x) | (f2bf(eav.y) << 16);
        slab[p] = r;
    }
}

// ---------------- phase 2: bucket offset + hist + scan + rowptr + place (one block/bucket) --------
__global__ __launch_bounds__(512) void k_place(const int* __restrict__ cursor,
                                               const uint2* __restrict__ slab,
                                               int* __restrict__ rowptr,
                                               uint2* __restrict__ csr) {
    __shared__ int hist[BUKW];
    __shared__ int cur[BUKW];
    __shared__ int s[512];
    int b = blockIdx.x;
    int t = threadIdx.x;
    int node0 = b * BUKW;
    int begin = b * CAP;
    int cnt = cursor[b];
    // bucket offset = sum of counts of buckets < b (tree reduce over 200 cursors)
    s[t] = (t < NBUK && t < b) ? cursor[t] : 0;
    __syncthreads();
    for (int off = 256; off > 0; off >>= 1) {
        if (t < off) s[t] += s[t + off];
        __syncthreads();
    }
    int bOff = s[0];
    __syncthreads();
    for (int i = t; i < BUKW; i += 512) hist[i] = 0;
    __syncthreads();
    for (int i = t; i < cnt; i += 512) {
        uint2 r = slab[begin + i];
        atomicAdd(&hist[r.x >> 17], 1);
    }
    __syncthreads();
    int hv = (t < BUKW) ? hist[t] : 0;
    s[t] = hv;
    __syncthreads();
    for (int off = 1; off < 512; off <<= 1) {
        int u = (t >= off) ? s[t - off] : 0;
        __syncthreads();
        s[t] += u;
        __syncthreads();
    }
    if (t < BUKW) {
        int o = bOff + s[t] - hv;
        rowptr[node0 + t] = o;
        cur[t] = o;
    }
    if (b == NBUK - 1 && t == 0) rowptr[NN] = NE;
    __syncthreads();
    for (int i = t; i < cnt; i += 512) {
        uint2 r = slab[begin + i];         // L2 hit (just streamed)
        int dl = (int)(r.x >> 17);
        int p = atomicAdd(&cur[dl], 1);
        uint2 o;
        o.x = r.x & 0x1FFFFu;
        o.y = r.y;
        csr[p] = o;
    }
}

// ---------------- input projection ----------------
__global__ void k_input_proj(const float* __restrict__ x, const float* __restrict__ Wi,
                             const float* __restrict__ bi, float* __restrict__ h) {
    __shared__ float sW[IN_DIM * DD];
    __shared__ float sb[DD];
    int t = threadIdx.x;
    if (t < IN_DIM * DD) sW[t] = Wi[t];
    if (t < DD) sb[t] = bi[t];
    __syncthreads();
    int tid = blockIdx.x * blockDim.x + t;
    int n = tid / DD, d = tid - n * DD;
    if (n >= NN) return;
    float acc = sb[d];
    const float* xr = x + n * IN_DIM;
#pragma unroll
    for (int i = 0; i < IN_DIM; i++) acc += xr[i] * sW[i * DD + d];
    h[n * DS + d] = acc;
}

// ------- per-layer node pass: q (80-B rows), kv (100-B rows), skip in fp32 -------
__global__ void k_qkv_skip(const float* __restrict__ h,
                           const float* __restrict__ Wq, const float* __restrict__ bq,
                           const float* __restrict__ Wk, const float* __restrict__ bk,
                           const float* __restrict__ Wv, const float* __restrict__ bv,
                           const float* __restrict__ Ws, const float* __restrict__ bs,
                           __hip_bfloat16* __restrict__ q, __hip_bfloat16* __restrict__ kv,
                           float* __restrict__ hout) {
    __shared__ float sWq[DD * DD], sWk[DD * DD], sWv[DD * DD], sWs[DD * DD];
    __shared__ float sb[4 * DD];
    for (int i = threadIdx.x; i < DD * DD; i += blockDim.x) {
        sWq[i] = Wq[i]; sWk[i] = Wk[i]; sWv[i] = Wv[i]; sWs[i] = Ws[i];
    }
    if (threadIdx.x < DD) {
        sb[threadIdx.x]          = bq[threadIdx.x];
        sb[DD + threadIdx.x]     = bk[threadIdx.x];
        sb[2 * DD + threadIdx.x] = bv[threadIdx.x];
        sb[3 * DD + threadIdx.x] = bs[threadIdx.x];
    }
    __syncthreads();
    int tid = blockIdx.x * blockDim.x + threadIdx.x;
    int n = tid / DD, d = tid - n * DD;
    if (n >= NN) return;
    float aq = sb[d], ak = sb[DD + d], av = sb[2 * DD + d], asv = sb[3 * DD + d];
    const float* hr = h + (size_t)n * DS;
#pragma unroll
    for (int i = 0; i < DD; i++) {
        float hv = hr[i];
        aq  += hv * sWq[i * DD + d];
        ak  += hv * sWk[i * DD + d];
        av  += hv * sWv[i * DD + d];
        asv += hv * sWs[i * DD + d];
    }
    int h5 = d / 5, c5 = d - 5 * h5;
    q[(size_t)n * 40 + 8 * h5 + c5] = __float2bfloat16(aq * INV_SQRT_C);  // fold 1/sqrt(C)
    kv[(size_t)n * 50 + 10 * h5 + c5]     = __float2bfloat16(ak);
    kv[(size_t)n * 50 + 10 * h5 + 5 + c5] = __float2bfloat16(av);
    hout[(size_t)n * DS + d] = asv;
}

// ---------------- fused edge pass: 5 lanes = 5 heads per node; optional fused head ----------------
__global__ __launch_bounds__(256) void k_edge_fused(
    const int* __restrict__ rowptr, const uint2* __restrict__ csr,
    const float* __restrict__ We, const __hip_bfloat16* __restrict__ q,
    const __hip_bfloat16* __restrict__ kv, float* __restrict__ hout,
    int fuse_head, const float* __restrict__ Wo, const float* __restrict__ bo,
    float* __restrict__ out) {
    __shared__ float sWe[EDGE_DIM * DD];
    __shared__ float sWo[DD];
    __shared__ float sbo;
    if (threadIdx.x < EDGE_DIM * DD) sWe[threadIdx.x] = We[threadIdx.x];
    if (threadIdx.x < DD) sWo[threadIdx.x] = Wo[threadIdx.x];
    if (threadIdx.x == 0) sbo = bo[0];
    __syncthreads();
    int lane = threadIdx.x & 63;
    int wv   = threadIdx.x >> 6;
    int grp  = lane / 5;             // 0..12 (12 = idle lanes 60-63)
    int h    = lane - grp * 5;       // head
    int node = blockIdx.x * NPB + wv * 12 + grp;
    bool act = (grp < 12) && (node < NN);

    int beg = 0, end = 0;
    float qa0 = 0, qa1 = 0, qa2 = 0, qa3 = 0, qa4 = 0, qwx = 0, qwy = 0;
    if (act) {
        beg = rowptr[node];
        end = rowptr[node + 1];
        uint4 qc = *(const uint4*)(q + (size_t)node * 40 + 8 * h);  // 16-B aligned
        qa0 = bflo(qc.x); qa1 = bfhi(qc.x); qa2 = bflo(qc.y); qa3 = bfhi(qc.y); qa4 = bflo(qc.z);
        const float* wx = &sWe[5 * h];
        const float* wy = &sWe[DD + 5 * h];
        qwx = qa0 * wx[0] + qa1 * wx[1] + qa2 * wx[2] + qa3 * wx[3] + qa4 * wx[4];
        qwy = qa0 * wy[0] + qa1 * wy[1] + qa2 * wy[2] + qa3 * wy[3] + qa4 * wy[4];
    }

    float l = 0.f, Sx = 0.f, Sy = 0.f;
    float a0 = 0.f, a1 = 0.f, a2 = 0.f, a3 = 0.f, a4 = 0.f;

    int p = beg;
    uint2 rec;
    rec.x = 0; rec.y = 0;
    if (p < end) rec = csr[p];
    while (p < end) {
        int pn = p + 1;
        uint2 nrec = rec;
        if (pn < end) nrec = csr[pn];              // prefetch next record
        const unsigned int* kb =
            (const unsigned int*)(kv + (size_t)rec.x * 50 + 10 * h);  // byte 100*src+20h, 4-B aligned
        unsigned int u0 = kb[0], u1 = kb[1], u2 = kb[2], u3 = kb[3], u4 = kb[4];
        float eax = bflo(rec.y), eay = bfhi(rec.y);
        float k0 = bflo(u0), k1 = bfhi(u0), k2 = bflo(u1), k3 = bfhi(u1), k4 = bflo(u2);
        float v0 = bfhi(u2), v1 = bflo(u3), v2 = bfhi(u3), v3 = bflo(u4), v4 = bfhi(u4);
        float s = qa0 * k0 + qa1 * k1 + qa2 * k2 + qa3 * k3 + qa4 * k4
                + eax * qwx + eay * qwy;
        float cf = __expf(s);
        l  += cf;
        Sx += cf * eax;
        Sy += cf * eay;
        a0 += cf * v0; a1 += cf * v1; a2 += cf * v2; a3 += cf * v3; a4 += cf * v4;
        rec = nrec;
        p = pn;
    }

    float dot = 0.f;
    if (act) {
        float inv = 1.0f / (l + 1e-16f);
        const float* wx = &sWe[5 * h];
        const float* wy = &sWe[DD + 5 * h];
        float* ho = hout + (size_t)node * DS + 5 * h;
        float n0 = ho[0] + (a0 + Sx * wx[0] + Sy * wy[0]) * inv;
        float n1 = ho[1] + (a1 + Sx * wx[1] + Sy * wy[1]) * inv;
        float n2 = ho[2] + (a2 + Sx * wx[2] + Sy * wy[2]) * inv;
        float n3 = ho[3] + (a3 + Sx * wx[3] + Sy * wy[3]) * inv;
        float n4 = ho[4] + (a4 + Sx * wx[4] + Sy * wy[4]) * inv;
        ho[0] = n0; ho[1] = n1; ho[2] = n2; ho[3] = n3; ho[4] = n4;
        if (fuse_head) {
            const float* wo = &sWo[5 * h];
            dot = n0 * wo[0] + n1 * wo[1] + n2 * wo[2] + n3 * wo[3] + n4 * wo[4];
        }
    }
    if (fuse_head) {
        // sum the 5 head-lanes of each group (uniform shfl, all 64 lanes execute)
        float dsum = dot;
#pragma unroll
        for (int k = 1; k < 5; k++) dsum += __shfl(dot, (grp * 5 + k) & 63, 64);
        if (act && h == 0) out[node] = 1.0f / (1.0f + __expf(-(dsum + sbo)));
    }
}

extern "C" void kernel_launch(void* const* d_in, const int* in_sizes, int n_in,
                              void* d_out, int out_size, void* d_ws, size_t ws_size,
                              hipStream_t stream) {
    const float* x     = (const float*)d_in[0];
    const int*   ei    = (const int*)d_in[1];     // [2,E]: src=[0..E), dst=[E..2E)
    const float* ea    = (const float*)d_in[2];   // [E,2]
    const float* Wi    = (const float*)d_in[3];
    const float* bi    = (const float*)d_in[4];
    const float* Wq    = (const float*)d_in[5];
    const float* bq    = (const float*)d_in[6];
    const float* Wk    = (const float*)d_in[7];
    const float* bk    = (const float*)d_in[8];
    const float* Wv    = (const float*)d_in[9];
    const float* bv    = (const float*)d_in[10];
    const float* We    = (const float*)d_in[11];
    const float* Wskip = (const float*)d_in[12];
    const float* bskip = (const float*)d_in[13];
    const float* Wo    = (const float*)d_in[14];
    const float* bo    = (const float*)d_in[15];
    float* out = (float*)d_out;
    (void)in_sizes; (void)n_in; (void)out_size; (void)ws_size;

    char* wsb = (char*)d_ws;
    size_t off = 0;
    auto alloc = [&](size_t bytes) {
        void* p = wsb + off;
        off += (bytes + 127) & ~(size_t)127;
        return p;
    };
    uint2* slab   = (uint2*)alloc((size_t)NBUK * CAP * sizeof(uint2));       // 16 MB
    uint2* csr    = (uint2*)alloc((size_t)NE * sizeof(uint2));               // 12.8 MB
    __hip_bfloat16* kvrec = (__hip_bfloat16*)alloc((size_t)NN * 50 * 2);     // 10 MB
    __hip_bfloat16* qrec  = (__hip_bfloat16*)alloc((size_t)NN * 40 * 2);     // 8 MB
    float* hA     = (float*)alloc((size_t)NN * DS * sizeof(float));
    float* hB     = (float*)alloc((size_t)NN * DS * sizeof(float));
    int*   rowptr = (int*)alloc((size_t)(NN + 1) * sizeof(int));
    int*   cursor = (int*)alloc((size_t)NBUK * sizeof(int));

    dim3 blk(256);
    int gND = (NN * DD + 255) / 256;    // 9766

    // CSR build (every call — ws is re-poisoned)
    hipMemsetAsync(cursor, 0, (size_t)NBUK * sizeof(int), stream);
    k_part<<<KPB, blk, 0, stream>>>(ei, ea, cursor, slab);
    k_place<<<NBUK, dim3(512), 0, stream>>>(cursor, slab, rowptr, csr);

    k_input_proj<<<gND, blk, 0, stream>>>(x, Wi, bi, hA);

    float* hc = hA;
    float* hn = hB;
    for (int l = 0; l < 3; l++) {
        k_qkv_skip<<<gND, blk, 0, stream>>>(hc,
                                            Wq + (size_t)l * DD * DD, bq + (size_t)l * DD,
                                            Wk + (size_t)l * DD * DD, bk + (size_t)l * DD,
                                            Wv + (size_t)l * DD * DD, bv + (size_t)l * DD,
                                            Wskip + (size_t)l * DD * DD, bskip + (size_t)l * DD,
                                            qrec, kvrec, hn);
        k_edge_fused<<<NBLK, blk, 0, stream>>>(rowptr, csr,
                                               We + (size_t)l * EDGE_DIM * DD,
                                               qrec, kvrec, hn,
                                               (l == 2) ? 1 : 0, Wo, bo, out);
        float* t = hc; hc = hn; hn = t;
    }
}